// Round 17
// baseline (62.659 us; speedup 1.0000x reference)
//
#include <hip/hip_runtime.h>
#include <hip/hip_bf16.h>

#define SEQ 2048
#define HD 64
#define NBH 32
#define SCALE 0.125f
#define QSC 0.18033688011112042f   // 0.125 * log2(e)  -> softmax in exp2 domain

typedef __attribute__((ext_vector_type(4)))  float    f32x4;
typedef __attribute__((ext_vector_type(16))) float    f32x16;
typedef __attribute__((ext_vector_type(8)))  short    bf16x8;
typedef __attribute__((ext_vector_type(4)))  unsigned u32x4;

__device__ inline short f2bf(float f) {
    unsigned u = __builtin_bit_cast(unsigned, f);
    unsigned r = u + 0x7FFFu + ((u >> 16) & 1u);
    return (short)(r >> 16);
}

__device__ inline unsigned cvt2(float lo, float hi) {
    unsigned d;
    asm("v_cvt_pk_bf16_f32 %0, %1, %2" : "=v"(d) : "v"(lo), "v"(hi));
    return d;
}

// Detect mask element size (1-byte bool vs 4-byte), for the r1 fallback path only.
__global__ void detect_mask_kernel(const unsigned char* __restrict__ m, int n, int* flag) {
    if (threadIdx.x == 0) *flag = (m[n - 1] != 0) ? 1 : 4;
}

// Fused prepass (validated r12/r16; mask-width detect inlined).
// [0,512):    bitpack mask -> bitsT[64][2048]
// [512,2560): K fp32 -> bf16 granule-major tiles (wave frag = stride-16B linear)
// [2560,3584): V fp32 -> Vt granule-major with swap23 k-relabel
__global__ __launch_bounds__(256)
void prep_kernel(const unsigned char* __restrict__ m, int mn,
                 const float* __restrict__ K, const float* __restrict__ V,
                 unsigned* __restrict__ bits, short* __restrict__ Kb,
                 short* __restrict__ Vt) {
    __shared__ short t[64][65];
    const int b = blockIdx.x, tid = threadIdx.x;
    if (b < 512) {
        const bool e1 = (m[mn - 1] != 0);
        const int idx = b * 256 + tid;
        const int row = idx >> 6, w = idx & 63;
        const size_t base = (size_t)row * SEQ + w * 32;
        unsigned word = 0;
        if (e1) {
            #pragma unroll
            for (int i = 0; i < 32; ++i) word |= (unsigned)(m[base + i] != 0) << i;
        } else {
            const unsigned* m32 = (const unsigned*)m;
            #pragma unroll
            for (int i = 0; i < 32; ++i) word |= (unsigned)(m32[base + i] != 0) << i;
        }
        bits[(size_t)w * SEQ + row] = word;
    } else if (b < 2560) {
        const int g = (b - 512) * 256 + tid;     // granule index
        const size_t i = (size_t)g * 8;
        f32x4 a = *(const f32x4*)(K + i);
        f32x4 c = *(const f32x4*)(K + i + 4);
        bf16x8 o;
        #pragma unroll
        for (int j = 0; j < 4; ++j) { o[j] = f2bf(a[j]); o[4 + j] = f2bf(c[j]); }
        const int row = g >> 3;
        const int c8  = g & 7;
        const int bh  = row >> 11;
        const int r   = row & 2047;
        const int tt  = r >> 5;
        const int la  = r & 31;
        *(bf16x8*)(Kb + ((size_t)bh * 64 + tt) * 2048 + (c8 * 32 + la) * 8) = o;
    } else {
        const int bb = b - 2560;
        const int s0 = (bb & 31) * 64, bh = bb >> 5;
        const float* Vb = V + (size_t)bh * SEQ * HD;
        const int sr = tid >> 6, d = tid & 63;
        #pragma unroll
        for (int i = 0; i < 16; ++i) {
            const int s = i * 4 + sr;
            t[s][d] = f2bf(Vb[(size_t)(s0 + s) * HD + d]);
        }
        __syncthreads();
        short* o = Vt + (size_t)bh * HD * SEQ;
        const int dr = tid >> 6, sl = tid & 63;
        #pragma unroll
        for (int i = 0; i < 16; ++i) {
            const int dd = i * 4 + dr;
            const int s = s0 + sl;
            const int k = s & 31;
            const int p = (k & ~12) | ((k & 8) >> 1) | ((k & 4) << 1);   // swap bits 2,3
            const int mm = ((dd >> 5) << 1) | (p >> 4);
            const int hh = (p >> 3) & 1;
            o[(size_t)(s >> 5) * 2048 + ((mm * 2 + hh) * 32 + (dd & 31)) * 8 + (p & 7)] = t[sl][dd];
        }
    }
}

// ================= equal-duration chunk kernel (r17) =================
// Every block = ONE 16-tile (8-step) kv-chunk of some (qg,bh) -> 1280 blocks
// with (near-)identical lifetimes, so co-residency (~5 blocks/CU) holds for
// the WHOLE kernel. r15/r16's kv-half split balanced total work per CU but
// not duration: lifetimes {16,9,8,1} left the 16-step block running alone
// (occupancy 15-22% vs 50% static). Body = r15's proven step (reg-staged
// double-buffered shared-KV, fixed-scale softmax, zero-cross-lane P-pack).
// u -> (qg,c): u<16: qg=12+(u>>2),c=u&3 | u<28: qg=8+v/3,c=v%3 |
//              u<36: qg=4+(v>>1),c=v&1 | else qg=u-36,c=0   (heavy first)
__global__ __launch_bounds__(256, 2)
void attn_chunk_kernel(const float* __restrict__ Q, const short* __restrict__ Kb,
                       const short* __restrict__ Vt, const unsigned* __restrict__ bitsT,
                       short* __restrict__ Oh_ws, float* __restrict__ l_ws) {
    __shared__ __align__(16) short pool[16384];   // 32KB: kv staging, then oacc alias
    short* kpool = pool;
    short* vpool = pool + 8192;

    const int id = blockIdx.x;          // 0..1279
    const int bh = id & 31;
    const int u  = id >> 5;             // 0..39
    int qg, c;
    if (u < 16)      { qg = 12 + (u >> 2);                c = u & 3; }
    else if (u < 28) { const int v = u - 16; qg = 8 + v / 3; c = v % 3; }
    else if (u < 36) { const int v = u - 28; qg = 4 + (v >> 1); c = v & 1; }
    else             { qg = u - 36;                        c = 0; }

    const int tid  = threadIdx.x;
    const int wid  = tid >> 6;
    const int lane = tid & 63;
    const int la   = lane & 31;
    const int h    = lane >> 5;
    const int q0w  = qg * 128 + wid * 32;
    const int tstart = c * 16;
    const int tend   = min(tstart + 16, 4 * qg + 4);   // even count (multiple of 4 - multiple of 16)

    // Q as MFMA B-operand: col=q=la, k-elem i of chunk j -> d = j*16 + h*8 + i
    bf16x8 qf[4];
    {
        const float* qp = Q + (size_t)bh * SEQ * HD + (size_t)(q0w + la) * HD + h * 8;
        #pragma unroll
        for (int j = 0; j < 4; ++j) {
            f32x4 a0 = *(const f32x4*)(qp + j * 16);
            f32x4 a1 = *(const f32x4*)(qp + j * 16 + 4);
            #pragma unroll
            for (int i = 0; i < 4; ++i) {
                qf[j][i]     = f2bf(a0[i] * QSC);
                qf[j][4 + i] = f2bf(a1[i] * QSC);
            }
        }
    }

    f32x16 acc_o0 = {0,0,0,0,0,0,0,0,0,0,0,0,0,0,0,0};
    f32x16 acc_o1 = {0,0,0,0,0,0,0,0,0,0,0,0,0,0,0,0};
    float l_run = 0.f;

    const short* Ktg = Kb + (size_t)bh * 64 * 2048;
    const short* Vtg = Vt + (size_t)bh * 64 * 2048;
    const unsigned* bq = bitsT + q0w + la;
    const int bp = 4 * h;

    auto body = [&](const short* kb, const short* vb, unsigned mwx) {
        bf16x8 kfa = *(const bf16x8*)(kb + lane * 8);
        bf16x8 kfb = *(const bf16x8*)(kb + 512 + lane * 8);
        bf16x8 kfc = *(const bf16x8*)(kb + 1024 + lane * 8);
        bf16x8 kfd = *(const bf16x8*)(kb + 1536 + lane * 8);
        bf16x8 vf00 = *(const bf16x8*)(vb + lane * 8);
        bf16x8 vf01 = *(const bf16x8*)(vb + 512 + lane * 8);
        bf16x8 vf10 = *(const bf16x8*)(vb + 1024 + lane * 8);
        bf16x8 vf11 = *(const bf16x8*)(vb + 1536 + lane * 8);

        f32x16 sA = {0,0,0,0,0,0,0,0,0,0,0,0,0,0,0,0};
        f32x16 sB = {0,0,0,0,0,0,0,0,0,0,0,0,0,0,0,0};
        __builtin_amdgcn_s_setprio(1);
        sA = __builtin_amdgcn_mfma_f32_32x32x16_bf16(kfa, qf[0], sA, 0, 0, 0);
        sB = __builtin_amdgcn_mfma_f32_32x32x16_bf16(kfc, qf[2], sB, 0, 0, 0);
        sA = __builtin_amdgcn_mfma_f32_32x32x16_bf16(kfb, qf[1], sA, 0, 0, 0);
        sB = __builtin_amdgcn_mfma_f32_32x32x16_bf16(kfd, qf[3], sB, 0, 0, 0);
        __builtin_amdgcn_s_setprio(0);
        f32x16 s = sA + sB;

        #pragma unroll
        for (int r = 0; r < 16; ++r) {
            float e = __builtin_amdgcn_exp2f(s[r]);
            s[r] = ((mwx >> (bp + (r & 3) + 8 * (r >> 2))) & 1u) ? e : 0.f;
        }
        float ps = ((s[0] + s[1]) + (s[2] + s[3])) + ((s[4] + s[5]) + (s[6] + s[7]));
        ps += ((s[8] + s[9]) + (s[10] + s[11])) + ((s[12] + s[13]) + (s[14] + s[15]));
        l_run += ps;

        u32x4 t1 = {cvt2(s[0], s[1]),  cvt2(s[2], s[3]),
                    cvt2(s[4], s[5]),  cvt2(s[6], s[7])};
        u32x4 t2 = {cvt2(s[8], s[9]),  cvt2(s[10], s[11]),
                    cvt2(s[12], s[13]), cvt2(s[14], s[15])};
        bf16x8 pb1 = __builtin_bit_cast(bf16x8, t1);
        bf16x8 pb2 = __builtin_bit_cast(bf16x8, t2);

        __builtin_amdgcn_s_setprio(1);
        acc_o0 = __builtin_amdgcn_mfma_f32_32x32x16_bf16(vf00, pb1, acc_o0, 0, 0, 0);
        acc_o1 = __builtin_amdgcn_mfma_f32_32x32x16_bf16(vf10, pb1, acc_o1, 0, 0, 0);
        acc_o0 = __builtin_amdgcn_mfma_f32_32x32x16_bf16(vf01, pb2, acc_o0, 0, 0, 0);
        acc_o1 = __builtin_amdgcn_mfma_f32_32x32x16_bf16(vf11, pb2, acc_o1, 0, 0, 0);
        __builtin_amdgcn_s_setprio(0);
    };

    // ---- prologue: reg-stage tiles tstart, tstart+1 into buf 0 ----
    {
        bf16x8 k0 = *(const bf16x8*)(Ktg + (size_t)tstart * 2048 + tid * 8);
        bf16x8 k1 = *(const bf16x8*)(Ktg + (size_t)(tstart + 1) * 2048 + tid * 8);
        bf16x8 v0 = *(const bf16x8*)(Vtg + (size_t)tstart * 2048 + tid * 8);
        bf16x8 v1 = *(const bf16x8*)(Vtg + (size_t)(tstart + 1) * 2048 + tid * 8);
        *(bf16x8*)(kpool + tid * 8) = k0;
        *(bf16x8*)(kpool + 2048 + tid * 8) = k1;
        *(bf16x8*)(vpool + tid * 8) = v0;
        *(bf16x8*)(vpool + 2048 + tid * 8) = v1;
    }
    unsigned mw0 = bq[(size_t)tstart * SEQ];
    unsigned mw1 = bq[(size_t)(tstart + 1) * SEQ];

    int cur = 0;
    for (int t = tstart; t < tend; t += 2) {
        __syncthreads();   // buf[cur] staged; prior reads of buf[cur^1] done

        // ---- prefetch tiles t+2, t+3 to regs + masks (clamped on last iter) ----
        int tn0 = t + 2, tn1 = t + 3;
        if (t + 2 >= tend) { tn0 = t; tn1 = t + 1; }
        bf16x8 sk0 = *(const bf16x8*)(Ktg + (size_t)tn0 * 2048 + tid * 8);
        bf16x8 sk1 = *(const bf16x8*)(Ktg + (size_t)tn1 * 2048 + tid * 8);
        bf16x8 sv0 = *(const bf16x8*)(Vtg + (size_t)tn0 * 2048 + tid * 8);
        bf16x8 sv1 = *(const bf16x8*)(Vtg + (size_t)tn1 * 2048 + tid * 8);
        unsigned nmw0 = bq[(size_t)tn0 * SEQ];
        unsigned nmw1 = bq[(size_t)tn1 * SEQ];

        // ---- compute tiles t and t+1 ----
        body(kpool + cur * 4096, vpool + cur * 4096, mw0);
        body(kpool + cur * 4096 + 2048, vpool + cur * 4096 + 2048, mw1);

        // ---- write staged regs into the other buffer ----
        *(bf16x8*)(kpool + (cur ^ 1) * 4096 + tid * 8) = sk0;
        *(bf16x8*)(kpool + (cur ^ 1) * 4096 + 2048 + tid * 8) = sk1;
        *(bf16x8*)(vpool + (cur ^ 1) * 4096 + tid * 8) = sv0;
        *(bf16x8*)(vpool + (cur ^ 1) * 4096 + 2048 + tid * 8) = sv1;

        mw0 = nmw0; mw1 = nmw1;
        cur ^= 1;
    }

    const int slot = u * 32 + bh;

    // ---- per-wave l (cross-half merge once) + l store ----
    const float l_full = l_run + __shfl_xor(l_run, 32);
    const float invw = (l_full > 0.f) ? (1.f / l_full) : 0.f;
    if (h == 0) l_ws[(size_t)slot * 128 + wid * 32 + la] = l_full;

    __syncthreads();   // all kv reads done -> safe to alias pool as oacc

    // ---- stage normalized bf16 Ohat into aliased LDS, then coalesced ws write ----
    short (*oacc)[32][72] = (short (*)[32][72])pool;
    {
        unsigned short* orow = (unsigned short*)&oacc[wid][la][0];
        #pragma unroll
        for (int g2 = 0; g2 < 4; ++g2) {
            const int d0 = 8 * g2 + 4 * h;
            unsigned w0 = cvt2(acc_o0[4 * g2 + 0] * invw, acc_o0[4 * g2 + 1] * invw);
            unsigned w1 = cvt2(acc_o0[4 * g2 + 2] * invw, acc_o0[4 * g2 + 3] * invw);
            unsigned w2 = cvt2(acc_o1[4 * g2 + 0] * invw, acc_o1[4 * g2 + 1] * invw);
            unsigned w3 = cvt2(acc_o1[4 * g2 + 2] * invw, acc_o1[4 * g2 + 3] * invw);
            *(unsigned*)&orow[d0]      = w0;
            *(unsigned*)&orow[d0 + 2]  = w1;
            *(unsigned*)&orow[d0 + 32] = w2;
            *(unsigned*)&orow[d0 + 34] = w3;
        }
    }
    __syncthreads();

    {
        const int q  = tid >> 3;
        const int dc = (tid & 7) * 8;
        unsigned short* ob = (unsigned short*)Oh_ws + (size_t)slot * 8192;
        #pragma unroll
        for (int k = 0; k < 4; ++k) {
            u32x4 pk = *(const u32x4*)&oacc[k][q][dc];
            *(u32x4*)(ob + (k * 32 + q) * 64 + dc) = pk;
        }
    }
}

// Combine 1..4 chunk partials per (qg,bh): O = sum_c l_c*Ohat_c / sum_c l_c
__global__ __launch_bounds__(256)
void reduce_kernel(const short* __restrict__ Oh_ws, const float* __restrict__ l_ws,
                   float* __restrict__ Out) {
    const int id = blockIdx.x;           // 2048 = 16 qg x 32 bh x 4 row-subs
    const int group = id >> 2;           // qg*32 + bh
    const int sub = id & 3;
    const int qg = group >> 5, bh = group & 31;
    const int tid = threadIdx.x;
    const int q  = sub * 32 + (tid >> 3);    // row 0..127
    const int dc = (tid & 7) * 8;

    int u0, nch;
    if (qg >= 12)     { u0 = (qg - 12) * 4;      nch = 4; }
    else if (qg >= 8) { u0 = 16 + (qg - 8) * 3;  nch = 3; }
    else if (qg >= 4) { u0 = 28 + (qg - 4) * 2;  nch = 2; }
    else              { u0 = 36 + qg;            nch = 1; }

    float Lq = 0.f;
    float o[8] = {0, 0, 0, 0, 0, 0, 0, 0};
    for (int cc = 0; cc < nch; ++cc) {
        const size_t slot = (size_t)(u0 + cc) * 32 + bh;
        const float wl = l_ws[slot * 128 + q];
        Lq += wl;
        u32x4 pk = *(const u32x4*)((const unsigned short*)Oh_ws + slot * 8192 + q * 64 + dc);
        #pragma unroll
        for (int j = 0; j < 4; ++j) {
            float lo = __builtin_bit_cast(float, (pk[j] & 0xFFFFu) << 16);
            float hi = __builtin_bit_cast(float, pk[j] & 0xFFFF0000u);
            o[2 * j]     += wl * lo;
            o[2 * j + 1] += wl * hi;
        }
    }
    const float inv = 1.f / Lq;          // diagonal chunk guarantees Lq > 0
    float* op = Out + (size_t)bh * SEQ * HD + (size_t)(qg * 128 + q) * HD + dc;
    f32x4 o0v = {o[0] * inv, o[1] * inv, o[2] * inv, o[3] * inv};
    f32x4 o1v = {o[4] * inv, o[5] * inv, o[6] * inv, o[7] * inv};
    *(f32x4*)op       = o0v;
    *(f32x4*)(op + 4) = o1v;
}

// ============ r13 shared-KV monolithic kernel (mid fallback, 58us total) ============
__global__ __launch_bounds__(256, 2)
void attn_shared_kernel(const float* __restrict__ Q, const short* __restrict__ Kb,
                        const short* __restrict__ Vt, const unsigned* __restrict__ bitsT,
                        float* __restrict__ Out) {
    __shared__ __align__(16) short kbuf[2][2][2048];
    __shared__ __align__(16) short vbuf[2][2][2048];
    __shared__ short oacc[4][32][72];

    const int id   = blockIdx.x;
    const int bh   = id & 31;
    const int qg   = (id < 256) ? (15 - (id >> 5)) : ((id - 256) >> 5);
    const int tid  = threadIdx.x;
    const int wid  = tid >> 6;
    const int lane = tid & 63;
    const int la   = lane & 31;
    const int h    = lane >> 5;
    const int q0w  = qg * 128 + wid * 32;
    const int nt   = qg * 4 + 4;
    const size_t base = (size_t)bh * SEQ * HD;

    bf16x8 qf[4];
    {
        const float* qp = Q + base + (size_t)(q0w + la) * HD + h * 8;
        #pragma unroll
        for (int j = 0; j < 4; ++j) {
            f32x4 a0 = *(const f32x4*)(qp + j * 16);
            f32x4 a1 = *(const f32x4*)(qp + j * 16 + 4);
            #pragma unroll
            for (int i = 0; i < 4; ++i) {
                qf[j][i]     = f2bf(a0[i] * QSC);
                qf[j][4 + i] = f2bf(a1[i] * QSC);
            }
        }
    }

    f32x16 acc_o0 = {0,0,0,0,0,0,0,0,0,0,0,0,0,0,0,0};
    f32x16 acc_o1 = {0,0,0,0,0,0,0,0,0,0,0,0,0,0,0,0};
    float l_run = 0.f;

    const short* Ktg = Kb + (size_t)bh * 64 * 2048;
    const short* Vtg = Vt + (size_t)bh * 64 * 2048;
    const unsigned* bq = bitsT + q0w + la;
    const int bp = 4 * h;

    auto body = [&](const short* kb, const short* vb, unsigned mwx) {
        bf16x8 kfa = *(const bf16x8*)(kb + lane * 8);
        bf16x8 kfb = *(const bf16x8*)(kb + 512 + lane * 8);
        bf16x8 kfc = *(const bf16x8*)(kb + 1024 + lane * 8);
        bf16x8 kfd = *(const bf16x8*)(kb + 1536 + lane * 8);
        bf16x8 vf00 = *(const bf16x8*)(vb + lane * 8);
        bf16x8 vf01 = *(const bf16x8*)(vb + 512 + lane * 8);
        bf16x8 vf10 = *(const bf16x8*)(vb + 1024 + lane * 8);
        bf16x8 vf11 = *(const bf16x8*)(vb + 1536 + lane * 8);

        f32x16 sA = {0,0,0,0,0,0,0,0,0,0,0,0,0,0,0,0};
        f32x16 sB = {0,0,0,0,0,0,0,0,0,0,0,0,0,0,0,0};
        __builtin_amdgcn_s_setprio(1);
        sA = __builtin_amdgcn_mfma_f32_32x32x16_bf16(kfa, qf[0], sA, 0, 0, 0);
        sB = __builtin_amdgcn_mfma_f32_32x32x16_bf16(kfc, qf[2], sB, 0, 0, 0);
        sA = __builtin_amdgcn_mfma_f32_32x32x16_bf16(kfb, qf[1], sA, 0, 0, 0);
        sB = __builtin_amdgcn_mfma_f32_32x32x16_bf16(kfd, qf[3], sB, 0, 0, 0);
        __builtin_amdgcn_s_setprio(0);
        f32x16 s = sA + sB;

        #pragma unroll
        for (int r = 0; r < 16; ++r) {
            float e = __builtin_amdgcn_exp2f(s[r]);
            s[r] = ((mwx >> (bp + (r & 3) + 8 * (r >> 2))) & 1u) ? e : 0.f;
        }
        float ps = ((s[0] + s[1]) + (s[2] + s[3])) + ((s[4] + s[5]) + (s[6] + s[7]));
        ps += ((s[8] + s[9]) + (s[10] + s[11])) + ((s[12] + s[13]) + (s[14] + s[15]));
        l_run += ps;

        u32x4 t1 = {cvt2(s[0], s[1]),  cvt2(s[2], s[3]),
                    cvt2(s[4], s[5]),  cvt2(s[6], s[7])};
        u32x4 t2 = {cvt2(s[8], s[9]),  cvt2(s[10], s[11]),
                    cvt2(s[12], s[13]), cvt2(s[14], s[15])};
        bf16x8 pb1 = __builtin_bit_cast(bf16x8, t1);
        bf16x8 pb2 = __builtin_bit_cast(bf16x8, t2);

        __builtin_amdgcn_s_setprio(1);
        acc_o0 = __builtin_amdgcn_mfma_f32_32x32x16_bf16(vf00, pb1, acc_o0, 0, 0, 0);
        acc_o1 = __builtin_amdgcn_mfma_f32_32x32x16_bf16(vf10, pb1, acc_o1, 0, 0, 0);
        acc_o0 = __builtin_amdgcn_mfma_f32_32x32x16_bf16(vf01, pb2, acc_o0, 0, 0, 0);
        acc_o1 = __builtin_amdgcn_mfma_f32_32x32x16_bf16(vf11, pb2, acc_o1, 0, 0, 0);
        __builtin_amdgcn_s_setprio(0);
    };

    {
        bf16x8 k0 = *(const bf16x8*)(Ktg + (size_t)tid * 8);
        bf16x8 k1 = *(const bf16x8*)(Ktg + 2048 + (size_t)tid * 8);
        bf16x8 v0 = *(const bf16x8*)(Vtg + (size_t)tid * 8);
        bf16x8 v1 = *(const bf16x8*)(Vtg + 2048 + (size_t)tid * 8);
        *(bf16x8*)(&kbuf[0][0][0] + tid * 8) = k0;
        *(bf16x8*)(&kbuf[0][1][0] + tid * 8) = k1;
        *(bf16x8*)(&vbuf[0][0][0] + tid * 8) = v0;
        *(bf16x8*)(&vbuf[0][1][0] + tid * 8) = v1;
    }
    unsigned mw0 = bq[0];
    unsigned mw1 = bq[SEQ];

    int cur = 0;
    for (int t = 0; t < nt; t += 2) {
        __syncthreads();
        const int tn0 = (t + 2 < nt) ? t + 2 : t;
        const int tn1 = (t + 3 < nt) ? t + 3 : t;
        bf16x8 sk0 = *(const bf16x8*)(Ktg + (size_t)tn0 * 2048 + tid * 8);
        bf16x8 sk1 = *(const bf16x8*)(Ktg + (size_t)tn1 * 2048 + tid * 8);
        bf16x8 sv0 = *(const bf16x8*)(Vtg + (size_t)tn0 * 2048 + tid * 8);
        bf16x8 sv1 = *(const bf16x8*)(Vtg + (size_t)tn1 * 2048 + tid * 8);
        unsigned nmw0 = bq[(size_t)tn0 * SEQ];
        unsigned nmw1 = bq[(size_t)tn1 * SEQ];

        body(&kbuf[cur][0][0], &vbuf[cur][0][0], mw0);
        body(&kbuf[cur][1][0], &vbuf[cur][1][0], mw1);

        *(bf16x8*)(&kbuf[cur ^ 1][0][0] + tid * 8) = sk0;
        *(bf16x8*)(&kbuf[cur ^ 1][1][0] + tid * 8) = sk1;
        *(bf16x8*)(&vbuf[cur ^ 1][0][0] + tid * 8) = sv0;
        *(bf16x8*)(&vbuf[cur ^ 1][1][0] + tid * 8) = sv1;

        mw0 = nmw0; mw1 = nmw1;
        cur ^= 1;
    }

    {
        const float l_full = l_run + __shfl_xor(l_run, 32);
        const float invw = 1.f / l_full;
        unsigned short* orow = (unsigned short*)&oacc[wid][la][0];
        #pragma unroll
        for (int g = 0; g < 4; ++g) {
            const int d0 = 8 * g + 4 * h;
            unsigned w0 = cvt2(acc_o0[4 * g + 0] * invw, acc_o0[4 * g + 1] * invw);
            unsigned w1 = cvt2(acc_o0[4 * g + 2] * invw, acc_o0[4 * g + 3] * invw);
            unsigned w2 = cvt2(acc_o1[4 * g + 0] * invw, acc_o1[4 * g + 1] * invw);
            unsigned w3 = cvt2(acc_o1[4 * g + 2] * invw, acc_o1[4 * g + 3] * invw);
            *(unsigned*)&orow[d0]      = w0;
            *(unsigned*)&orow[d0 + 2]  = w1;
            *(unsigned*)&orow[d0 + 32] = w2;
            *(unsigned*)&orow[d0 + 34] = w3;
        }
    }
    __syncthreads();

    {
        const int q  = tid >> 3;
        const int dc = (tid & 7) * 8;
        #pragma unroll
        for (int k = 0; k < 4; ++k) {
            u32x4 pk = *(const u32x4*)&oacc[k][q][dc];
            float o[8];
            #pragma unroll
            for (int j = 0; j < 4; ++j) {
                o[2 * j]     = __builtin_bit_cast(float, (pk[j] & 0xFFFFu) << 16);
                o[2 * j + 1] = __builtin_bit_cast(float, pk[j] & 0xFFFF0000u);
            }
            float* op = Out + base + (size_t)(qg * 128 + k * 32 + q) * HD + dc;
            f32x4 o0v = {o[0], o[1], o[2], o[3]};
            f32x4 o1v = {o[4], o[5], o[6], o[7]};
            *(f32x4*)op       = o0v;
            *(f32x4*)(op + 4) = o1v;
        }
    }
}

// ---------------- fallback (round-1 kernel) if ws too small ----------------
__global__ __launch_bounds__(256)
void attn_kernel(const float* __restrict__ Q, const float* __restrict__ K,
                 const float* __restrict__ V, const unsigned char* __restrict__ mask,
                 const int* __restrict__ flag, float* __restrict__ Out) {
    __shared__ short plds[4][16][40];
    const int esz  = *flag;
    const int bh   = blockIdx.y;
    const int wid  = threadIdx.x >> 6;
    const int lane = threadIdx.x & 63;
    const int l16  = lane & 15;
    const int hi   = lane >> 4;
    const int q0   = blockIdx.x * 64 + wid * 16;
    const size_t base = (size_t)bh * SEQ * HD;
    const float* Qb = Q + base;
    const float* Kb = K + base;
    const float* Vb = V + base;
    const unsigned int* mask32 = (const unsigned int*)mask;
    bf16x8 qf[2];
    {
        const float* qp = Qb + (size_t)(q0 + l16) * HD + hi * 8;
        f32x4 a0 = *(const f32x4*)(qp);
        f32x4 a1 = *(const f32x4*)(qp + 4);
        f32x4 a2 = *(const f32x4*)(qp + 32);
        f32x4 a3 = *(const f32x4*)(qp + 36);
        #pragma unroll
        for (int i = 0; i < 4; ++i) {
            qf[0][i] = f2bf(a0[i]); qf[0][4 + i] = f2bf(a1[i]);
            qf[1][i] = f2bf(a2[i]); qf[1][4 + i] = f2bf(a3[i]);
        }
    }
    f32x4 acc_o[4] = {f32x4{0,0,0,0}, f32x4{0,0,0,0}, f32x4{0,0,0,0}, f32x4{0,0,0,0}};
    float m_run[4], l_run[4];
    #pragma unroll
    for (int j = 0; j < 4; ++j) { m_run[j] = -__builtin_inff(); l_run[j] = 0.f; }
    const int kv_end = q0 + 16;
    for (int kv = 0; kv < kv_end; kv += 32) {
        f32x4 acc_s[2] = {f32x4{0,0,0,0}, f32x4{0,0,0,0}};
        #pragma unroll
        for (int t = 0; t < 2; ++t) {
            const float* kp = Kb + (size_t)(kv + 16 * t + l16) * HD + hi * 8;
            f32x4 b0 = *(const f32x4*)(kp);
            f32x4 b1 = *(const f32x4*)(kp + 4);
            f32x4 b2 = *(const f32x4*)(kp + 32);
            f32x4 b3 = *(const f32x4*)(kp + 36);
            bf16x8 kf0, kf1;
            #pragma unroll
            for (int i = 0; i < 4; ++i) {
                kf0[i] = f2bf(b0[i]); kf0[4 + i] = f2bf(b1[i]);
                kf1[i] = f2bf(b2[i]); kf1[4 + i] = f2bf(b3[i]);
            }
            acc_s[t] = __builtin_amdgcn_mfma_f32_16x16x32_bf16(qf[0], kf0, acc_s[t], 0, 0, 0);
            acc_s[t] = __builtin_amdgcn_mfma_f32_16x16x32_bf16(qf[1], kf1, acc_s[t], 0, 0, 0);
        }
        float s[2][4];
        #pragma unroll
        for (int t = 0; t < 2; ++t) {
            const int k = kv + 16 * t + l16;
            #pragma unroll
            for (int j = 0; j < 4; ++j) {
                const int qrow = q0 + hi * 4 + j;
                const size_t midx = (size_t)qrow * SEQ + k;
                const bool mv = (esz == 1) ? (mask[midx] != 0) : (mask32[midx] != 0);
                s[t][j] = mv ? acc_s[t][j] * SCALE : -__builtin_inff();
            }
        }
        float mnew[4], r[4];
        #pragma unroll
        for (int j = 0; j < 4; ++j) {
            float v = fmaxf(s[0][j], s[1][j]);
            #pragma unroll
            for (int off = 1; off < 16; off <<= 1) v = fmaxf(v, __shfl_xor(v, off));
            mnew[j] = fmaxf(m_run[j], v);
            r[j] = (m_run[j] > -__builtin_inff()) ? __expf(m_run[j] - mnew[j]) : 0.f;
        }
        float p[2][4];
        #pragma unroll
        for (int j = 0; j < 4; ++j) {
            float ps = 0.f;
            #pragma unroll
            for (int t = 0; t < 2; ++t) {
                p[t][j] = (s[t][j] > -__builtin_inff()) ? __expf(s[t][j] - mnew[j]) : 0.f;
                ps += p[t][j];
            }
            #pragma unroll
            for (int off = 1; off < 16; off <<= 1) ps += __shfl_xor(ps, off);
            l_run[j] = l_run[j] * r[j] + ps;
            m_run[j] = mnew[j];
            #pragma unroll
            for (int t2 = 0; t2 < 4; ++t2) acc_o[t2][j] *= r[j];
        }
        #pragma unroll
        for (int t = 0; t < 2; ++t)
            #pragma unroll
            for (int j = 0; j < 4; ++j)
                plds[wid][hi * 4 + j][16 * t + l16] = f2bf(p[t][j]);
        bf16x8 pa = *(bf16x8*)&plds[wid][l16][hi * 8];
        #pragma unroll
        for (int t2 = 0; t2 < 4; ++t2) {
            const float* vp = Vb + (size_t)(kv + hi * 8) * HD + 16 * t2 + l16;
            bf16x8 vf;
            #pragma unroll
            for (int i = 0; i < 8; ++i) vf[i] = f2bf(vp[(size_t)i * HD]);
            acc_o[t2] = __builtin_amdgcn_mfma_f32_16x16x32_bf16(pa, vf, acc_o[t2], 0, 0, 0);
        }
    }
    #pragma unroll
    for (int j = 0; j < 4; ++j) {
        const float inv = 1.f / l_run[j];
        const int qrow = q0 + hi * 4 + j;
        float* op = Out + base + (size_t)qrow * HD + l16;
        #pragma unroll
        for (int t2 = 0; t2 < 4; ++t2) op[16 * t2] = acc_o[t2][j] * inv;
    }
}

extern "C" void kernel_launch(void* const* d_in, const int* in_sizes, int n_in,
                              void* d_out, int out_size, void* d_ws, size_t ws_size,
                              hipStream_t stream) {
    const float* Q = (const float*)d_in[0];
    const float* K = (const float*)d_in[1];
    const float* V = (const float*)d_in[2];
    const unsigned char* mask = (const unsigned char*)d_in[3];

    const size_t bitsB = (size_t)SEQ * (SEQ / 32) * 4;          // 512 KB
    const size_t kvB   = (size_t)NBH * SEQ * HD * 2;            // 8 MB
    const size_t flagB = 256;
    const size_t ohB   = (size_t)1280 * 8192 * 2;               // 21 MB (1280 chunk slots)
    const size_t lB    = (size_t)1280 * 128 * 4;                // 0.65 MB
    const size_t need_mono  = bitsB + 2 * kvB + flagB;          // 16.5 MB
    const size_t need_chunk = need_mono + ohB + lB;             // ~38.2 MB

    if (ws_size >= need_mono) {
        unsigned* bits = (unsigned*)d_ws;
        short* Kb = (short*)((char*)d_ws + bitsB);
        short* Vt = (short*)((char*)d_ws + bitsB + kvB);

        prep_kernel<<<dim3(3584), dim3(256), 0, stream>>>(mask, in_sizes[3], K, V, bits, Kb, Vt);

        if (ws_size >= need_chunk) {
            short* Oh_ws = (short*)((char*)d_ws + need_mono);
            float* l_ws  = (float*)((char*)d_ws + need_mono + ohB);
            attn_chunk_kernel<<<dim3(1280), dim3(256), 0, stream>>>(Q, Kb, Vt, bits, Oh_ws, l_ws);
            reduce_kernel<<<dim3(2048), dim3(256), 0, stream>>>(Oh_ws, l_ws, (float*)d_out);
        } else {
            attn_shared_kernel<<<dim3(512), dim3(256), 0, stream>>>(Q, Kb, Vt, bits, (float*)d_out);
        }
    } else {
        int* flag = (int*)d_ws;
        detect_mask_kernel<<<dim3(1), dim3(64), 0, stream>>>(mask, in_sizes[3], flag);
        attn_kernel<<<dim3(SEQ / 64, NBH), dim3(256), 0, stream>>>(Q, K, V, mask, flag, (float*)d_out);
    }
}

// Round 18
// 54.378 us; speedup vs baseline: 1.1523x; 1.1523x over previous
//
#include <hip/hip_runtime.h>
#include <hip/hip_bf16.h>

#define SEQ 2048
#define HD 64
#define NBH 32
#define SCALE 0.125f
#define QSC 0.18033688011112042f   // 0.125 * log2(e)  -> softmax in exp2 domain

typedef __attribute__((ext_vector_type(4)))  float    f32x4;
typedef __attribute__((ext_vector_type(16))) float    f32x16;
typedef __attribute__((ext_vector_type(8)))  short    bf16x8;
typedef __attribute__((ext_vector_type(4)))  unsigned u32x4;

__device__ inline short f2bf(float f) {
    unsigned u = __builtin_bit_cast(unsigned, f);
    unsigned r = u + 0x7FFFu + ((u >> 16) & 1u);
    return (short)(r >> 16);
}

__device__ inline unsigned cvt2(float lo, float hi) {
    unsigned d;
    asm("v_cvt_pk_bf16_f32 %0, %1, %2" : "=v"(d) : "v"(lo), "v"(hi));
    return d;
}

// Detect mask element size (1-byte bool vs 4-byte), for the r1 fallback path only.
__global__ void detect_mask_kernel(const unsigned char* __restrict__ m, int n, int* flag) {
    if (threadIdx.x == 0) *flag = (m[n - 1] != 0) ? 1 : 4;
}

// Fused prepass (validated r12/r16; mask-width detect inlined).
// [0,512):    bitpack mask -> bitsT[64][2048]
// [512,2560): K fp32 -> bf16 granule-major tiles (wave frag = stride-16B linear)
// [2560,3584): V fp32 -> Vt granule-major with swap23 k-relabel
__global__ __launch_bounds__(256)
void prep_kernel(const unsigned char* __restrict__ m, int mn,
                 const float* __restrict__ K, const float* __restrict__ V,
                 unsigned* __restrict__ bits, short* __restrict__ Kb,
                 short* __restrict__ Vt) {
    __shared__ short t[64][65];
    const int b = blockIdx.x, tid = threadIdx.x;
    if (b < 512) {
        const bool e1 = (m[mn - 1] != 0);
        const int idx = b * 256 + tid;
        const int row = idx >> 6, w = idx & 63;
        const size_t base = (size_t)row * SEQ + w * 32;
        unsigned word = 0;
        if (e1) {
            #pragma unroll
            for (int i = 0; i < 32; ++i) word |= (unsigned)(m[base + i] != 0) << i;
        } else {
            const unsigned* m32 = (const unsigned*)m;
            #pragma unroll
            for (int i = 0; i < 32; ++i) word |= (unsigned)(m32[base + i] != 0) << i;
        }
        bits[(size_t)w * SEQ + row] = word;
    } else if (b < 2560) {
        const int g = (b - 512) * 256 + tid;     // granule index
        const size_t i = (size_t)g * 8;
        f32x4 a = *(const f32x4*)(K + i);
        f32x4 c = *(const f32x4*)(K + i + 4);
        bf16x8 o;
        #pragma unroll
        for (int j = 0; j < 4; ++j) { o[j] = f2bf(a[j]); o[4 + j] = f2bf(c[j]); }
        const int row = g >> 3;
        const int c8  = g & 7;
        const int bh  = row >> 11;
        const int r   = row & 2047;
        const int tt  = r >> 5;
        const int la  = r & 31;
        *(bf16x8*)(Kb + ((size_t)bh * 64 + tt) * 2048 + (c8 * 32 + la) * 8) = o;
    } else {
        const int bb = b - 2560;
        const int s0 = (bb & 31) * 64, bh = bb >> 5;
        const float* Vb = V + (size_t)bh * SEQ * HD;
        const int sr = tid >> 6, d = tid & 63;
        #pragma unroll
        for (int i = 0; i < 16; ++i) {
            const int s = i * 4 + sr;
            t[s][d] = f2bf(Vb[(size_t)(s0 + s) * HD + d]);
        }
        __syncthreads();
        short* o = Vt + (size_t)bh * HD * SEQ;
        const int dr = tid >> 6, sl = tid & 63;
        #pragma unroll
        for (int i = 0; i < 16; ++i) {
            const int dd = i * 4 + dr;
            const int s = s0 + sl;
            const int k = s & 31;
            const int p = (k & ~12) | ((k & 8) >> 1) | ((k & 4) << 1);   // swap bits 2,3
            const int mm = ((dd >> 5) << 1) | (p >> 4);
            const int hh = (p >> 3) & 1;
            o[(size_t)(s >> 5) * 2048 + ((mm * 2 + hh) * 32 + (dd & 31)) * 8 + (p & 7)] = t[sl][dd];
        }
    }
}

// ================= shared-KV monolith, 4-tile steps (r18) =================
// r13's proven structure (512 blocks, balanced pairing, direct Out write, no
// reduce pass) with the barrier interval widened to FOUR kv-tiles: 4 independent
// bodies (~2400cy interleavable compute) per window fully cover prefetch +
// ds_read latency, and barrier/drain overhead amortizes 2x vs the 2-tile step.
// Supply experiments (r15-r17: 2x/2.5x blocks) moved nothing -- the per-step
// serial chain is the wall, so shorten/amortize the chain instead.
// LDS: 2 bufs x 4 tiles x (K 4KB + V 4KB) = 64KB; epilogue oacc aliased onto
// the pool (r15-validated). (256,2): ~150 arch VGPR + 32 acc, no-squeeze.
__global__ __launch_bounds__(256, 2)
void attn_shared4_kernel(const float* __restrict__ Q, const short* __restrict__ Kb,
                         const short* __restrict__ Vt, const unsigned* __restrict__ bitsT,
                         float* __restrict__ Out) {
    __shared__ __align__(16) short pool[32768];   // 64KB
    short* kpool = pool;              // [buf][tile][2048] shorts
    short* vpool = pool + 16384;

    const int id   = blockIdx.x;
    const int bh   = id & 31;
    const int qg   = (id < 256) ? (15 - (id >> 5)) : ((id - 256) >> 5);
    const int tid  = threadIdx.x;
    const int wid  = tid >> 6;
    const int lane = tid & 63;
    const int la   = lane & 31;
    const int h    = lane >> 5;
    const int q0w  = qg * 128 + wid * 32;
    const int nt   = qg * 4 + 4;              // multiple of 4
    const size_t base = (size_t)bh * SEQ * HD;

    // Q as MFMA B-operand: col=q=la, k-elem i of chunk j -> d = j*16 + h*8 + i
    bf16x8 qf[4];
    {
        const float* qp = Q + base + (size_t)(q0w + la) * HD + h * 8;
        #pragma unroll
        for (int j = 0; j < 4; ++j) {
            f32x4 a0 = *(const f32x4*)(qp + j * 16);
            f32x4 a1 = *(const f32x4*)(qp + j * 16 + 4);
            #pragma unroll
            for (int i = 0; i < 4; ++i) {
                qf[j][i]     = f2bf(a0[i] * QSC);
                qf[j][4 + i] = f2bf(a1[i] * QSC);
            }
        }
    }

    f32x16 acc_o0 = {0,0,0,0,0,0,0,0,0,0,0,0,0,0,0,0};
    f32x16 acc_o1 = {0,0,0,0,0,0,0,0,0,0,0,0,0,0,0,0};
    float l_run = 0.f;

    const short* Ktg = Kb + (size_t)bh * 64 * 2048;
    const short* Vtg = Vt + (size_t)bh * 64 * 2048;
    const unsigned* bq = bitsT + q0w + la;
    const int bp = 4 * h;

    auto body = [&](const short* kb, const short* vb, unsigned mwx) {
        bf16x8 kfa = *(const bf16x8*)(kb + lane * 8);
        bf16x8 kfb = *(const bf16x8*)(kb + 512 + lane * 8);
        bf16x8 kfc = *(const bf16x8*)(kb + 1024 + lane * 8);
        bf16x8 kfd = *(const bf16x8*)(kb + 1536 + lane * 8);
        bf16x8 vf00 = *(const bf16x8*)(vb + lane * 8);
        bf16x8 vf01 = *(const bf16x8*)(vb + 512 + lane * 8);
        bf16x8 vf10 = *(const bf16x8*)(vb + 1024 + lane * 8);
        bf16x8 vf11 = *(const bf16x8*)(vb + 1536 + lane * 8);

        f32x16 sA = {0,0,0,0,0,0,0,0,0,0,0,0,0,0,0,0};
        f32x16 sB = {0,0,0,0,0,0,0,0,0,0,0,0,0,0,0,0};
        __builtin_amdgcn_s_setprio(1);
        sA = __builtin_amdgcn_mfma_f32_32x32x16_bf16(kfa, qf[0], sA, 0, 0, 0);
        sB = __builtin_amdgcn_mfma_f32_32x32x16_bf16(kfc, qf[2], sB, 0, 0, 0);
        sA = __builtin_amdgcn_mfma_f32_32x32x16_bf16(kfb, qf[1], sA, 0, 0, 0);
        sB = __builtin_amdgcn_mfma_f32_32x32x16_bf16(kfd, qf[3], sB, 0, 0, 0);
        __builtin_amdgcn_s_setprio(0);
        f32x16 s = sA + sB;

        #pragma unroll
        for (int r = 0; r < 16; ++r) {
            float e = __builtin_amdgcn_exp2f(s[r]);
            s[r] = ((mwx >> (bp + (r & 3) + 8 * (r >> 2))) & 1u) ? e : 0.f;
        }
        float ps = ((s[0] + s[1]) + (s[2] + s[3])) + ((s[4] + s[5]) + (s[6] + s[7]));
        ps += ((s[8] + s[9]) + (s[10] + s[11])) + ((s[12] + s[13]) + (s[14] + s[15]));
        l_run += ps;

        u32x4 t1 = {cvt2(s[0], s[1]),  cvt2(s[2], s[3]),
                    cvt2(s[4], s[5]),  cvt2(s[6], s[7])};
        u32x4 t2 = {cvt2(s[8], s[9]),  cvt2(s[10], s[11]),
                    cvt2(s[12], s[13]), cvt2(s[14], s[15])};
        bf16x8 pb1 = __builtin_bit_cast(bf16x8, t1);
        bf16x8 pb2 = __builtin_bit_cast(bf16x8, t2);

        __builtin_amdgcn_s_setprio(1);
        acc_o0 = __builtin_amdgcn_mfma_f32_32x32x16_bf16(vf00, pb1, acc_o0, 0, 0, 0);
        acc_o1 = __builtin_amdgcn_mfma_f32_32x32x16_bf16(vf10, pb1, acc_o1, 0, 0, 0);
        acc_o0 = __builtin_amdgcn_mfma_f32_32x32x16_bf16(vf01, pb2, acc_o0, 0, 0, 0);
        acc_o1 = __builtin_amdgcn_mfma_f32_32x32x16_bf16(vf11, pb2, acc_o1, 0, 0, 0);
        __builtin_amdgcn_s_setprio(0);
    };

    // ---- prologue: reg-stage tiles 0..3 into buf 0 ----
    #pragma unroll
    for (int i = 0; i < 4; ++i) {
        bf16x8 k = *(const bf16x8*)(Ktg + (size_t)i * 2048 + tid * 8);
        bf16x8 v = *(const bf16x8*)(Vtg + (size_t)i * 2048 + tid * 8);
        *(bf16x8*)(kpool + i * 2048 + tid * 8) = k;
        *(bf16x8*)(vpool + i * 2048 + tid * 8) = v;
    }
    unsigned mw0 = bq[0 * SEQ], mw1 = bq[1 * SEQ], mw2 = bq[2 * SEQ], mw3 = bq[3 * SEQ];

    int cur = 0;
    for (int t = 0; t < nt; t += 4) {
        __syncthreads();   // buf[cur] (tiles t..t+3) staged; prior reads of buf[cur^1] done

        // ---- prefetch tiles t+4..t+7 to regs + masks (clamped on last iter) ----
        const int tb = (t + 4 < nt) ? t + 4 : t;
        bf16x8 sk0 = *(const bf16x8*)(Ktg + (size_t)(tb + 0) * 2048 + tid * 8);
        bf16x8 sk1 = *(const bf16x8*)(Ktg + (size_t)(tb + 1) * 2048 + tid * 8);
        bf16x8 sk2 = *(const bf16x8*)(Ktg + (size_t)(tb + 2) * 2048 + tid * 8);
        bf16x8 sk3 = *(const bf16x8*)(Ktg + (size_t)(tb + 3) * 2048 + tid * 8);
        bf16x8 sv0 = *(const bf16x8*)(Vtg + (size_t)(tb + 0) * 2048 + tid * 8);
        bf16x8 sv1 = *(const bf16x8*)(Vtg + (size_t)(tb + 1) * 2048 + tid * 8);
        bf16x8 sv2 = *(const bf16x8*)(Vtg + (size_t)(tb + 2) * 2048 + tid * 8);
        bf16x8 sv3 = *(const bf16x8*)(Vtg + (size_t)(tb + 3) * 2048 + tid * 8);
        unsigned nmw0 = bq[(size_t)(tb + 0) * SEQ];
        unsigned nmw1 = bq[(size_t)(tb + 1) * SEQ];
        unsigned nmw2 = bq[(size_t)(tb + 2) * SEQ];
        unsigned nmw3 = bq[(size_t)(tb + 3) * SEQ];

        // ---- compute tiles t..t+3 (independent bodies) ----
        const short* kc = kpool + cur * 8192;
        const short* vc = vpool + cur * 8192;
        body(kc,        vc,        mw0);
        body(kc + 2048, vc + 2048, mw1);
        body(kc + 4096, vc + 4096, mw2);
        body(kc + 6144, vc + 6144, mw3);

        // ---- write staged regs into the other buffer ----
        short* kn = kpool + (cur ^ 1) * 8192;
        short* vn = vpool + (cur ^ 1) * 8192;
        *(bf16x8*)(kn + tid * 8)        = sk0;
        *(bf16x8*)(kn + 2048 + tid * 8) = sk1;
        *(bf16x8*)(kn + 4096 + tid * 8) = sk2;
        *(bf16x8*)(kn + 6144 + tid * 8) = sk3;
        *(bf16x8*)(vn + tid * 8)        = sv0;
        *(bf16x8*)(vn + 2048 + tid * 8) = sv1;
        *(bf16x8*)(vn + 4096 + tid * 8) = sv2;
        *(bf16x8*)(vn + 6144 + tid * 8) = sv3;

        mw0 = nmw0; mw1 = nmw1; mw2 = nmw2; mw3 = nmw3;
        cur ^= 1;
    }

    // ---- epilogue: per-wave normalize, bf16 stage in ALIASED LDS, coalesced write ----
    const float l_full = l_run + __shfl_xor(l_run, 32);
    const float invw = 1.f / l_full;   // diag always unmasked -> l_full > 0

    __syncthreads();   // all kv reads done -> safe to alias pool as oacc

    short (*oacc)[32][72] = (short (*)[32][72])pool;
    {
        unsigned short* orow = (unsigned short*)&oacc[wid][la][0];
        #pragma unroll
        for (int g = 0; g < 4; ++g) {
            const int d0 = 8 * g + 4 * h;
            unsigned w0 = cvt2(acc_o0[4 * g + 0] * invw, acc_o0[4 * g + 1] * invw);
            unsigned w1 = cvt2(acc_o0[4 * g + 2] * invw, acc_o0[4 * g + 3] * invw);
            unsigned w2 = cvt2(acc_o1[4 * g + 0] * invw, acc_o1[4 * g + 1] * invw);
            unsigned w3 = cvt2(acc_o1[4 * g + 2] * invw, acc_o1[4 * g + 3] * invw);
            *(unsigned*)&orow[d0]      = w0;
            *(unsigned*)&orow[d0 + 2]  = w1;
            *(unsigned*)&orow[d0 + 32] = w2;
            *(unsigned*)&orow[d0 + 34] = w3;
        }
    }
    __syncthreads();

    {
        const int q  = tid >> 3;
        const int dc = (tid & 7) * 8;
        #pragma unroll
        for (int k = 0; k < 4; ++k) {
            u32x4 pk = *(const u32x4*)&oacc[k][q][dc];
            float o[8];
            #pragma unroll
            for (int j = 0; j < 4; ++j) {
                o[2 * j]     = __builtin_bit_cast(float, (pk[j] & 0xFFFFu) << 16);
                o[2 * j + 1] = __builtin_bit_cast(float, pk[j] & 0xFFFF0000u);
            }
            float* op = Out + base + (size_t)(qg * 128 + k * 32 + q) * HD + dc;
            f32x4 o0v = {o[0], o[1], o[2], o[3]};
            f32x4 o1v = {o[4], o[5], o[6], o[7]};
            *(f32x4*)op       = o0v;
            *(f32x4*)(op + 4) = o1v;
        }
    }
}

// ---------------- fallback (round-1 kernel) if ws too small ----------------
__global__ __launch_bounds__(256)
void attn_kernel(const float* __restrict__ Q, const float* __restrict__ K,
                 const float* __restrict__ V, const unsigned char* __restrict__ mask,
                 const int* __restrict__ flag, float* __restrict__ Out) {
    __shared__ short plds[4][16][40];
    const int esz  = *flag;
    const int bh   = blockIdx.y;
    const int wid  = threadIdx.x >> 6;
    const int lane = threadIdx.x & 63;
    const int l16  = lane & 15;
    const int hi   = lane >> 4;
    const int q0   = blockIdx.x * 64 + wid * 16;
    const size_t base = (size_t)bh * SEQ * HD;
    const float* Qb = Q + base;
    const float* Kb = K + base;
    const float* Vb = V + base;
    const unsigned int* mask32 = (const unsigned int*)mask;
    bf16x8 qf[2];
    {
        const float* qp = Qb + (size_t)(q0 + l16) * HD + hi * 8;
        f32x4 a0 = *(const f32x4*)(qp);
        f32x4 a1 = *(const f32x4*)(qp + 4);
        f32x4 a2 = *(const f32x4*)(qp + 32);
        f32x4 a3 = *(const f32x4*)(qp + 36);
        #pragma unroll
        for (int i = 0; i < 4; ++i) {
            qf[0][i] = f2bf(a0[i]); qf[0][4 + i] = f2bf(a1[i]);
            qf[1][i] = f2bf(a2[i]); qf[1][4 + i] = f2bf(a3[i]);
        }
    }
    f32x4 acc_o[4] = {f32x4{0,0,0,0}, f32x4{0,0,0,0}, f32x4{0,0,0,0}, f32x4{0,0,0,0}};
    float m_run[4], l_run[4];
    #pragma unroll
    for (int j = 0; j < 4; ++j) { m_run[j] = -__builtin_inff(); l_run[j] = 0.f; }
    const int kv_end = q0 + 16;
    for (int kv = 0; kv < kv_end; kv += 32) {
        f32x4 acc_s[2] = {f32x4{0,0,0,0}, f32x4{0,0,0,0}};
        #pragma unroll
        for (int t = 0; t < 2; ++t) {
            const float* kp = Kb + (size_t)(kv + 16 * t + l16) * HD + hi * 8;
            f32x4 b0 = *(const f32x4*)(kp);
            f32x4 b1 = *(const f32x4*)(kp + 4);
            f32x4 b2 = *(const f32x4*)(kp + 32);
            f32x4 b3 = *(const f32x4*)(kp + 36);
            bf16x8 kf0, kf1;
            #pragma unroll
            for (int i = 0; i < 4; ++i) {
                kf0[i] = f2bf(b0[i]); kf0[4 + i] = f2bf(b1[i]);
                kf1[i] = f2bf(b2[i]); kf1[4 + i] = f2bf(b3[i]);
            }
            acc_s[t] = __builtin_amdgcn_mfma_f32_16x16x32_bf16(qf[0], kf0, acc_s[t], 0, 0, 0);
            acc_s[t] = __builtin_amdgcn_mfma_f32_16x16x32_bf16(qf[1], kf1, acc_s[t], 0, 0, 0);
        }
        float s[2][4];
        #pragma unroll
        for (int t = 0; t < 2; ++t) {
            const int k = kv + 16 * t + l16;
            #pragma unroll
            for (int j = 0; j < 4; ++j) {
                const int qrow = q0 + hi * 4 + j;
                const size_t midx = (size_t)qrow * SEQ + k;
                const bool mv = (esz == 1) ? (mask[midx] != 0) : (mask32[midx] != 0);
                s[t][j] = mv ? acc_s[t][j] * SCALE : -__builtin_inff();
            }
        }
        float mnew[4], r[4];
        #pragma unroll
        for (int j = 0; j < 4; ++j) {
            float v = fmaxf(s[0][j], s[1][j]);
            #pragma unroll
            for (int off = 1; off < 16; off <<= 1) v = fmaxf(v, __shfl_xor(v, off));
            mnew[j] = fmaxf(m_run[j], v);
            r[j] = (m_run[j] > -__builtin_inff()) ? __expf(m_run[j] - mnew[j]) : 0.f;
        }
        float p[2][4];
        #pragma unroll
        for (int j = 0; j < 4; ++j) {
            float ps = 0.f;
            #pragma unroll
            for (int t = 0; t < 2; ++t) {
                p[t][j] = (s[t][j] > -__builtin_inff()) ? __expf(s[t][j] - mnew[j]) : 0.f;
                ps += p[t][j];
            }
            #pragma unroll
            for (int off = 1; off < 16; off <<= 1) ps += __shfl_xor(ps, off);
            l_run[j] = l_run[j] * r[j] + ps;
            m_run[j] = mnew[j];
            #pragma unroll
            for (int t2 = 0; t2 < 4; ++t2) acc_o[t2][j] *= r[j];
        }
        #pragma unroll
        for (int t = 0; t < 2; ++t)
            #pragma unroll
            for (int j = 0; j < 4; ++j)
                plds[wid][hi * 4 + j][16 * t + l16] = f2bf(p[t][j]);
        bf16x8 pa = *(bf16x8*)&plds[wid][l16][hi * 8];
        #pragma unroll
        for (int t2 = 0; t2 < 4; ++t2) {
            const float* vp = Vb + (size_t)(kv + hi * 8) * HD + 16 * t2 + l16;
            bf16x8 vf;
            #pragma unroll
            for (int i = 0; i < 8; ++i) vf[i] = f2bf(vp[(size_t)i * HD]);
            acc_o[t2] = __builtin_amdgcn_mfma_f32_16x16x32_bf16(pa, vf, acc_o[t2], 0, 0, 0);
        }
    }
    #pragma unroll
    for (int j = 0; j < 4; ++j) {
        const float inv = 1.f / l_run[j];
        const int qrow = q0 + hi * 4 + j;
        float* op = Out + base + (size_t)qrow * HD + l16;
        #pragma unroll
        for (int t2 = 0; t2 < 4; ++t2) op[16 * t2] = acc_o[t2][j] * inv;
    }
}

extern "C" void kernel_launch(void* const* d_in, const int* in_sizes, int n_in,
                              void* d_out, int out_size, void* d_ws, size_t ws_size,
                              hipStream_t stream) {
    const float* Q = (const float*)d_in[0];
    const float* K = (const float*)d_in[1];
    const float* V = (const float*)d_in[2];
    const unsigned char* mask = (const unsigned char*)d_in[3];

    const size_t bitsB = (size_t)SEQ * (SEQ / 32) * 4;          // 512 KB
    const size_t kvB   = (size_t)NBH * SEQ * HD * 2;            // 8 MB
    const size_t need  = bitsB + 2 * kvB + 256;                 // 16.5 MB

    if (ws_size >= need) {
        unsigned* bits = (unsigned*)d_ws;
        short* Kb = (short*)((char*)d_ws + bitsB);
        short* Vt = (short*)((char*)d_ws + bitsB + kvB);

        prep_kernel<<<dim3(3584), dim3(256), 0, stream>>>(mask, in_sizes[3], K, V, bits, Kb, Vt);
        attn_shared4_kernel<<<dim3(512), dim3(256), 0, stream>>>(Q, Kb, Vt, bits, (float*)d_out);
    } else {
        int* flag = (int*)d_ws;
        detect_mask_kernel<<<dim3(1), dim3(64), 0, stream>>>(mask, in_sizes[3], flag);
        attn_kernel<<<dim3(SEQ / 64, NBH), dim3(256), 0, stream>>>(Q, K, V, mask, flag, (float*)d_out);
    }
}

// Round 19
// 53.438 us; speedup vs baseline: 1.1726x; 1.0176x over previous
//
#include <hip/hip_runtime.h>
#include <hip/hip_bf16.h>

#define SEQ 2048
#define HD 64
#define NBH 32
#define SCALE 0.125f
#define QSC 0.18033688011112042f   // 0.125 * log2(e)  -> softmax in exp2 domain

typedef __attribute__((ext_vector_type(4)))  float    f32x4;
typedef __attribute__((ext_vector_type(16))) float    f32x16;
typedef __attribute__((ext_vector_type(8)))  short    bf16x8;
typedef __attribute__((ext_vector_type(4)))  unsigned u32x4;

__device__ inline short f2bf(float f) {
    unsigned u = __builtin_bit_cast(unsigned, f);
    unsigned r = u + 0x7FFFu + ((u >> 16) & 1u);
    return (short)(r >> 16);
}

__device__ inline unsigned cvt2(float lo, float hi) {
    unsigned d;
    asm("v_cvt_pk_bf16_f32 %0, %1, %2" : "=v"(d) : "v"(lo), "v"(hi));
    return d;
}

// Detect mask element size (1-byte bool vs 4-byte), for the r1 fallback path only.
__global__ void detect_mask_kernel(const unsigned char* __restrict__ m, int n, int* flag) {
    if (threadIdx.x == 0) *flag = (m[n - 1] != 0) ? 1 : 4;
}

// Fused prepass (validated r12/r16; mask-width detect inlined).
// [0,512):    bitpack mask -> bitsT[64][2048]
// [512,2560): K fp32 -> bf16 granule-major tiles (wave frag = stride-16B linear)
// [2560,3584): V fp32 -> Vt granule-major with swap23 k-relabel
__global__ __launch_bounds__(256)
void prep_kernel(const unsigned char* __restrict__ m, int mn,
                 const float* __restrict__ K, const float* __restrict__ V,
                 unsigned* __restrict__ bits, short* __restrict__ Kb,
                 short* __restrict__ Vt) {
    __shared__ short t[64][65];
    const int b = blockIdx.x, tid = threadIdx.x;
    if (b < 512) {
        const bool e1 = (m[mn - 1] != 0);
        const int idx = b * 256 + tid;
        const int row = idx >> 6, w = idx & 63;
        const size_t base = (size_t)row * SEQ + w * 32;
        unsigned word = 0;
        if (e1) {
            #pragma unroll
            for (int i = 0; i < 32; ++i) word |= (unsigned)(m[base + i] != 0) << i;
        } else {
            const unsigned* m32 = (const unsigned*)m;
            #pragma unroll
            for (int i = 0; i < 32; ++i) word |= (unsigned)(m32[base + i] != 0) << i;
        }
        bits[(size_t)w * SEQ + row] = word;
    } else if (b < 2560) {
        const int g = (b - 512) * 256 + tid;     // granule index
        const size_t i = (size_t)g * 8;
        f32x4 a = *(const f32x4*)(K + i);
        f32x4 c = *(const f32x4*)(K + i + 4);
        bf16x8 o;
        #pragma unroll
        for (int j = 0; j < 4; ++j) { o[j] = f2bf(a[j]); o[4 + j] = f2bf(c[j]); }
        const int row = g >> 3;
        const int c8  = g & 7;
        const int bh  = row >> 11;
        const int r   = row & 2047;
        const int tt  = r >> 5;
        const int la  = r & 31;
        *(bf16x8*)(Kb + ((size_t)bh * 64 + tt) * 2048 + (c8 * 32 + la) * 8) = o;
    } else {
        const int bb = b - 2560;
        const int s0 = (bb & 31) * 64, bh = bb >> 5;
        const float* Vb = V + (size_t)bh * SEQ * HD;
        const int sr = tid >> 6, d = tid & 63;
        #pragma unroll
        for (int i = 0; i < 16; ++i) {
            const int s = i * 4 + sr;
            t[s][d] = f2bf(Vb[(size_t)(s0 + s) * HD + d]);
        }
        __syncthreads();
        short* o = Vt + (size_t)bh * HD * SEQ;
        const int dr = tid >> 6, sl = tid & 63;
        #pragma unroll
        for (int i = 0; i < 16; ++i) {
            const int dd = i * 4 + dr;
            const int s = s0 + sl;
            const int k = s & 31;
            const int p = (k & ~12) | ((k & 8) >> 1) | ((k & 4) << 1);   // swap bits 2,3
            const int mm = ((dd >> 5) << 1) | (p >> 4);
            const int hh = (p >> 3) & 1;
            o[(size_t)(s >> 5) * 2048 + ((mm * 2 + hh) * 32 + (dd & 31)) * 8 + (p & 7)] = t[sl][dd];
        }
    }
}

// ================= shared-KV monolith, 2-tile steps + aliased pool (r19) =================
// Best-of-each consolidation: r13's 2-tile window body (fastest measured
// monolith, 46.3us vs r18's 4-tile 49.5us), r15's aliased 32KB LDS pool
// (epilogue oacc overlays the kv staging after a barrier), r18's 2-launch
// structure (no detect / no reduce pass), and a single dependent 4-MFMA QK
// chain (m119: dependent accumulate chains run at throughput) replacing the
// sA/sB split -- deletes 16 VALU adds per body.
// 512 blocks, balanced pairing (id<256: qg=15-(id>>5), else qg=(id-256)>>5):
// CU pairs sum to 17 windows; bh = id&31 keeps same-bh blocks on one XCD.
__global__ __launch_bounds__(256, 2)
void attn_shared2_kernel(const float* __restrict__ Q, const short* __restrict__ Kb,
                         const short* __restrict__ Vt, const unsigned* __restrict__ bitsT,
                         float* __restrict__ Out) {
    __shared__ __align__(16) short pool[16384];   // 32KB: [k 2buf x 2tile][v 2buf x 2tile]
    short* kpool = pool;              // buf stride 4096, tile stride 2048
    short* vpool = pool + 8192;

    const int id   = blockIdx.x;
    const int bh   = id & 31;
    const int qg   = (id < 256) ? (15 - (id >> 5)) : ((id - 256) >> 5);
    const int tid  = threadIdx.x;
    const int wid  = tid >> 6;
    const int lane = tid & 63;
    const int la   = lane & 31;
    const int h    = lane >> 5;
    const int q0w  = qg * 128 + wid * 32;
    const int nt   = qg * 4 + 4;              // multiple of 4
    const size_t base = (size_t)bh * SEQ * HD;

    // Q as MFMA B-operand: col=q=la, k-elem i of chunk j -> d = j*16 + h*8 + i
    bf16x8 qf[4];
    {
        const float* qp = Q + base + (size_t)(q0w + la) * HD + h * 8;
        #pragma unroll
        for (int j = 0; j < 4; ++j) {
            f32x4 a0 = *(const f32x4*)(qp + j * 16);
            f32x4 a1 = *(const f32x4*)(qp + j * 16 + 4);
            #pragma unroll
            for (int i = 0; i < 4; ++i) {
                qf[j][i]     = f2bf(a0[i] * QSC);
                qf[j][4 + i] = f2bf(a1[i] * QSC);
            }
        }
    }

    f32x16 acc_o0 = {0,0,0,0,0,0,0,0,0,0,0,0,0,0,0,0};
    f32x16 acc_o1 = {0,0,0,0,0,0,0,0,0,0,0,0,0,0,0,0};
    float l_run = 0.f;

    const short* Ktg = Kb + (size_t)bh * 64 * 2048;
    const short* Vtg = Vt + (size_t)bh * 64 * 2048;
    const unsigned* bq = bitsT + q0w + la;
    const int bp = 4 * h;

    auto body = [&](const short* kb, const short* vb, unsigned mwx) {
        bf16x8 kfa = *(const bf16x8*)(kb + lane * 8);
        bf16x8 kfb = *(const bf16x8*)(kb + 512 + lane * 8);
        bf16x8 kfc = *(const bf16x8*)(kb + 1024 + lane * 8);
        bf16x8 kfd = *(const bf16x8*)(kb + 1536 + lane * 8);
        bf16x8 vf00 = *(const bf16x8*)(vb + lane * 8);
        bf16x8 vf01 = *(const bf16x8*)(vb + 512 + lane * 8);
        bf16x8 vf10 = *(const bf16x8*)(vb + 1024 + lane * 8);
        bf16x8 vf11 = *(const bf16x8*)(vb + 1536 + lane * 8);

        // single dependent 4-MFMA QK chain (accumulate chaining is
        // throughput-rate on the matrix pipe; saves the 16 sA+sB adds)
        f32x16 s = {0,0,0,0,0,0,0,0,0,0,0,0,0,0,0,0};
        __builtin_amdgcn_s_setprio(1);
        s = __builtin_amdgcn_mfma_f32_32x32x16_bf16(kfa, qf[0], s, 0, 0, 0);
        s = __builtin_amdgcn_mfma_f32_32x32x16_bf16(kfb, qf[1], s, 0, 0, 0);
        s = __builtin_amdgcn_mfma_f32_32x32x16_bf16(kfc, qf[2], s, 0, 0, 0);
        s = __builtin_amdgcn_mfma_f32_32x32x16_bf16(kfd, qf[3], s, 0, 0, 0);
        __builtin_amdgcn_s_setprio(0);

        #pragma unroll
        for (int r = 0; r < 16; ++r) {
            float e = __builtin_amdgcn_exp2f(s[r]);
            s[r] = ((mwx >> (bp + (r & 3) + 8 * (r >> 2))) & 1u) ? e : 0.f;
        }
        float ps = ((s[0] + s[1]) + (s[2] + s[3])) + ((s[4] + s[5]) + (s[6] + s[7]));
        ps += ((s[8] + s[9]) + (s[10] + s[11])) + ((s[12] + s[13]) + (s[14] + s[15]));
        l_run += ps;

        u32x4 t1 = {cvt2(s[0], s[1]),  cvt2(s[2], s[3]),
                    cvt2(s[4], s[5]),  cvt2(s[6], s[7])};
        u32x4 t2 = {cvt2(s[8], s[9]),  cvt2(s[10], s[11]),
                    cvt2(s[12], s[13]), cvt2(s[14], s[15])};
        bf16x8 pb1 = __builtin_bit_cast(bf16x8, t1);
        bf16x8 pb2 = __builtin_bit_cast(bf16x8, t2);

        __builtin_amdgcn_s_setprio(1);
        acc_o0 = __builtin_amdgcn_mfma_f32_32x32x16_bf16(vf00, pb1, acc_o0, 0, 0, 0);
        acc_o1 = __builtin_amdgcn_mfma_f32_32x32x16_bf16(vf10, pb1, acc_o1, 0, 0, 0);
        acc_o0 = __builtin_amdgcn_mfma_f32_32x32x16_bf16(vf01, pb2, acc_o0, 0, 0, 0);
        acc_o1 = __builtin_amdgcn_mfma_f32_32x32x16_bf16(vf11, pb2, acc_o1, 0, 0, 0);
        __builtin_amdgcn_s_setprio(0);
    };

    // ---- prologue: reg-stage tiles 0,1 into buf 0 ----
    {
        bf16x8 k0 = *(const bf16x8*)(Ktg + (size_t)tid * 8);
        bf16x8 k1 = *(const bf16x8*)(Ktg + 2048 + (size_t)tid * 8);
        bf16x8 v0 = *(const bf16x8*)(Vtg + (size_t)tid * 8);
        bf16x8 v1 = *(const bf16x8*)(Vtg + 2048 + (size_t)tid * 8);
        *(bf16x8*)(kpool + tid * 8) = k0;
        *(bf16x8*)(kpool + 2048 + tid * 8) = k1;
        *(bf16x8*)(vpool + tid * 8) = v0;
        *(bf16x8*)(vpool + 2048 + tid * 8) = v1;
    }
    unsigned mw0 = bq[0];
    unsigned mw1 = bq[SEQ];

    int cur = 0;
    for (int t = 0; t < nt; t += 2) {
        __syncthreads();   // buf[cur] staged; prior reads of buf[cur^1] done

        // ---- prefetch tiles t+2, t+3 to regs + masks (clamped on last iter) ----
        const int tn0 = (t + 2 < nt) ? t + 2 : t;
        const int tn1 = (t + 3 < nt) ? t + 3 : t;
        bf16x8 sk0 = *(const bf16x8*)(Ktg + (size_t)tn0 * 2048 + tid * 8);
        bf16x8 sk1 = *(const bf16x8*)(Ktg + (size_t)tn1 * 2048 + tid * 8);
        bf16x8 sv0 = *(const bf16x8*)(Vtg + (size_t)tn0 * 2048 + tid * 8);
        bf16x8 sv1 = *(const bf16x8*)(Vtg + (size_t)tn1 * 2048 + tid * 8);
        unsigned nmw0 = bq[(size_t)tn0 * SEQ];
        unsigned nmw1 = bq[(size_t)tn1 * SEQ];

        // ---- compute tiles t, t+1 ----
        body(kpool + cur * 4096,        vpool + cur * 4096,        mw0);
        body(kpool + cur * 4096 + 2048, vpool + cur * 4096 + 2048, mw1);

        // ---- write staged regs into the other buffer ----
        *(bf16x8*)(kpool + (cur ^ 1) * 4096 + tid * 8)        = sk0;
        *(bf16x8*)(kpool + (cur ^ 1) * 4096 + 2048 + tid * 8) = sk1;
        *(bf16x8*)(vpool + (cur ^ 1) * 4096 + tid * 8)        = sv0;
        *(bf16x8*)(vpool + (cur ^ 1) * 4096 + 2048 + tid * 8) = sv1;

        mw0 = nmw0; mw1 = nmw1;
        cur ^= 1;
    }

    // ---- epilogue: per-wave normalize, bf16 stage in ALIASED LDS, coalesced write ----
    const float l_full = l_run + __shfl_xor(l_run, 32);
    const float invw = 1.f / l_full;   // diag always unmasked -> l_full > 0

    __syncthreads();   // all kv reads done -> safe to alias pool as oacc

    short (*oacc)[32][72] = (short (*)[32][72])pool;
    {
        unsigned short* orow = (unsigned short*)&oacc[wid][la][0];
        #pragma unroll
        for (int g = 0; g < 4; ++g) {
            const int d0 = 8 * g + 4 * h;
            unsigned w0 = cvt2(acc_o0[4 * g + 0] * invw, acc_o0[4 * g + 1] * invw);
            unsigned w1 = cvt2(acc_o0[4 * g + 2] * invw, acc_o0[4 * g + 3] * invw);
            unsigned w2 = cvt2(acc_o1[4 * g + 0] * invw, acc_o1[4 * g + 1] * invw);
            unsigned w3 = cvt2(acc_o1[4 * g + 2] * invw, acc_o1[4 * g + 3] * invw);
            *(unsigned*)&orow[d0]      = w0;
            *(unsigned*)&orow[d0 + 2]  = w1;
            *(unsigned*)&orow[d0 + 32] = w2;
            *(unsigned*)&orow[d0 + 34] = w3;
        }
    }
    __syncthreads();

    {
        const int q  = tid >> 3;
        const int dc = (tid & 7) * 8;
        #pragma unroll
        for (int k = 0; k < 4; ++k) {
            u32x4 pk = *(const u32x4*)&oacc[k][q][dc];
            float o[8];
            #pragma unroll
            for (int j = 0; j < 4; ++j) {
                o[2 * j]     = __builtin_bit_cast(float, (pk[j] & 0xFFFFu) << 16);
                o[2 * j + 1] = __builtin_bit_cast(float, pk[j] & 0xFFFF0000u);
            }
            float* op = Out + base + (size_t)(qg * 128 + k * 32 + q) * HD + dc;
            f32x4 o0v = {o[0], o[1], o[2], o[3]};
            f32x4 o1v = {o[4], o[5], o[6], o[7]};
            *(f32x4*)op       = o0v;
            *(f32x4*)(op + 4) = o1v;
        }
    }
}

// ---------------- fallback (round-1 kernel) if ws too small ----------------
__global__ __launch_bounds__(256)
void attn_kernel(const float* __restrict__ Q, const float* __restrict__ K,
                 const float* __restrict__ V, const unsigned char* __restrict__ mask,
                 const int* __restrict__ flag, float* __restrict__ Out) {
    __shared__ short plds[4][16][40];
    const int esz  = *flag;
    const int bh   = blockIdx.y;
    const int wid  = threadIdx.x >> 6;
    const int lane = threadIdx.x & 63;
    const int l16  = lane & 15;
    const int hi   = lane >> 4;
    const int q0   = blockIdx.x * 64 + wid * 16;
    const size_t base = (size_t)bh * SEQ * HD;
    const float* Qb = Q + base;
    const float* Kb = K + base;
    const float* Vb = V + base;
    const unsigned int* mask32 = (const unsigned int*)mask;
    bf16x8 qf[2];
    {
        const float* qp = Qb + (size_t)(q0 + l16) * HD + hi * 8;
        f32x4 a0 = *(const f32x4*)(qp);
        f32x4 a1 = *(const f32x4*)(qp + 4);
        f32x4 a2 = *(const f32x4*)(qp + 32);
        f32x4 a3 = *(const f32x4*)(qp + 36);
        #pragma unroll
        for (int i = 0; i < 4; ++i) {
            qf[0][i] = f2bf(a0[i]); qf[0][4 + i] = f2bf(a1[i]);
            qf[1][i] = f2bf(a2[i]); qf[1][4 + i] = f2bf(a3[i]);
        }
    }
    f32x4 acc_o[4] = {f32x4{0,0,0,0}, f32x4{0,0,0,0}, f32x4{0,0,0,0}, f32x4{0,0,0,0}};
    float m_run[4], l_run[4];
    #pragma unroll
    for (int j = 0; j < 4; ++j) { m_run[j] = -__builtin_inff(); l_run[j] = 0.f; }
    const int kv_end = q0 + 16;
    for (int kv = 0; kv < kv_end; kv += 32) {
        f32x4 acc_s[2] = {f32x4{0,0,0,0}, f32x4{0,0,0,0}};
        #pragma unroll
        for (int t = 0; t < 2; ++t) {
            const float* kp = Kb + (size_t)(kv + 16 * t + l16) * HD + hi * 8;
            f32x4 b0 = *(const f32x4*)(kp);
            f32x4 b1 = *(const f32x4*)(kp + 4);
            f32x4 b2 = *(const f32x4*)(kp + 32);
            f32x4 b3 = *(const f32x4*)(kp + 36);
            bf16x8 kf0, kf1;
            #pragma unroll
            for (int i = 0; i < 4; ++i) {
                kf0[i] = f2bf(b0[i]); kf0[4 + i] = f2bf(b1[i]);
                kf1[i] = f2bf(b2[i]); kf1[4 + i] = f2bf(b3[i]);
            }
            acc_s[t] = __builtin_amdgcn_mfma_f32_16x16x32_bf16(qf[0], kf0, acc_s[t], 0, 0, 0);
            acc_s[t] = __builtin_amdgcn_mfma_f32_16x16x32_bf16(qf[1], kf1, acc_s[t], 0, 0, 0);
        }
        float s[2][4];
        #pragma unroll
        for (int t = 0; t < 2; ++t) {
            const int k = kv + 16 * t + l16;
            #pragma unroll
            for (int j = 0; j < 4; ++j) {
                const int qrow = q0 + hi * 4 + j;
                const size_t midx = (size_t)qrow * SEQ + k;
                const bool mv = (esz == 1) ? (mask[midx] != 0) : (mask32[midx] != 0);
                s[t][j] = mv ? acc_s[t][j] * SCALE : -__builtin_inff();
            }
        }
        float mnew[4], r[4];
        #pragma unroll
        for (int j = 0; j < 4; ++j) {
            float v = fmaxf(s[0][j], s[1][j]);
            #pragma unroll
            for (int off = 1; off < 16; off <<= 1) v = fmaxf(v, __shfl_xor(v, off));
            mnew[j] = fmaxf(m_run[j], v);
            r[j] = (m_run[j] > -__builtin_inff()) ? __expf(m_run[j] - mnew[j]) : 0.f;
        }
        float p[2][4];
        #pragma unroll
        for (int j = 0; j < 4; ++j) {
            float ps = 0.f;
            #pragma unroll
            for (int t = 0; t < 2; ++t) {
                p[t][j] = (s[t][j] > -__builtin_inff()) ? __expf(s[t][j] - mnew[j]) : 0.f;
                ps += p[t][j];
            }
            #pragma unroll
            for (int off = 1; off < 16; off <<= 1) ps += __shfl_xor(ps, off);
            l_run[j] = l_run[j] * r[j] + ps;
            m_run[j] = mnew[j];
            #pragma unroll
            for (int t2 = 0; t2 < 4; ++t2) acc_o[t2][j] *= r[j];
        }
        #pragma unroll
        for (int t = 0; t < 2; ++t)
            #pragma unroll
            for (int j = 0; j < 4; ++j)
                plds[wid][hi * 4 + j][16 * t + l16] = f2bf(p[t][j]);
        bf16x8 pa = *(bf16x8*)&plds[wid][l16][hi * 8];
        #pragma unroll
        for (int t2 = 0; t2 < 4; ++t2) {
            const float* vp = Vb + (size_t)(kv + hi * 8) * HD + 16 * t2 + l16;
            bf16x8 vf;
            #pragma unroll
            for (int i = 0; i < 8; ++i) vf[i] = f2bf(vp[(size_t)i * HD]);
            acc_o[t2] = __builtin_amdgcn_mfma_f32_16x16x32_bf16(pa, vf, acc_o[t2], 0, 0, 0);
        }
    }
    #pragma unroll
    for (int j = 0; j < 4; ++j) {
        const float inv = 1.f / l_run[j];
        const int qrow = q0 + hi * 4 + j;
        float* op = Out + base + (size_t)qrow * HD + l16;
        #pragma unroll
        for (int t2 = 0; t2 < 4; ++t2) op[16 * t2] = acc_o[t2][j] * inv;
    }
}

extern "C" void kernel_launch(void* const* d_in, const int* in_sizes, int n_in,
                              void* d_out, int out_size, void* d_ws, size_t ws_size,
                              hipStream_t stream) {
    const float* Q = (const float*)d_in[0];
    const float* K = (const float*)d_in[1];
    const float* V = (const float*)d_in[2];
    const unsigned char* mask = (const unsigned char*)d_in[3];

    const size_t bitsB = (size_t)SEQ * (SEQ / 32) * 4;          // 512 KB
    const size_t kvB   = (size_t)NBH * SEQ * HD * 2;            // 8 MB
    const size_t need  = bitsB + 2 * kvB + 256;                 // 16.5 MB

    if (ws_size >= need) {
        unsigned* bits = (unsigned*)d_ws;
        short* Kb = (short*)((char*)d_ws + bitsB);
        short* Vt = (short*)((char*)d_ws + bitsB + kvB);

        prep_kernel<<<dim3(3584), dim3(256), 0, stream>>>(mask, in_sizes[3], K, V, bits, Kb, Vt);
        attn_shared2_kernel<<<dim3(512), dim3(256), 0, stream>>>(Q, Kb, Vt, bits, (float*)d_out);
    } else {
        int* flag = (int*)d_ws;
        detect_mask_kernel<<<dim3(1), dim3(64), 0, stream>>>(mask, in_sizes[3], flag);
        attn_kernel<<<dim3(SEQ / 64, NBH), dim3(256), 0, stream>>>(Q, K, V, mask, flag, (float*)d_out);
    }
}